// Round 5
// baseline (804.003 us; speedup 1.0000x reference)
//
#include <hip/hip_runtime.h>
#include <hip/hip_bf16.h>

#define N_NODES 100000
#define IN_F    128
#define OUT_F   64
#define ROWS_PER_BLK 32
#define INV_KEEP (1.0f / 0.9f)

#define RPB_LOG 7                 // rows per bucket = 128
#define RPB (1 << RPB_LOG)
#define NB  ((N_NODES + RPB - 1) / RPB)   // 782 buckets
#define BIN_CHUNK 4096
#define BIN_BS 1024
#define ACC_BS 1024
#define ACC_NW (ACC_BS / 64)      // 16 waves

// ---------------------------------------------------------------------------
// Kernel 1: hidden = dropout(x @ W + b) -> bf16 [N_NODES x OUT_F] in ws.
// ---------------------------------------------------------------------------
__global__ __launch_bounds__(256) void gemm_dropout_kernel(
    const float* __restrict__ x, const float* __restrict__ w,
    const float* __restrict__ bias, const void* __restrict__ mask,
    ushort* __restrict__ hidden) {
  __shared__ float wlds[IN_F * OUT_F];          // 32 KB
  __shared__ float xlds[ROWS_PER_BLK * IN_F];   // 16 KB
  __shared__ int mask_is_u8;

  const int tid = threadIdx.x;
  const int rowbase = blockIdx.x * ROWS_PER_BLK;

  const float4* w4 = (const float4*)w;
  float4* wl4 = (float4*)wlds;
  #pragma unroll
  for (int i = 0; i < (IN_F * OUT_F / 4) / 256; ++i)
    wl4[tid + i * 256] = w4[tid + i * 256];

  const float4* x4 = (const float4*)(x + (size_t)rowbase * IN_F);
  float4* xl4 = (float4*)xlds;
  #pragma unroll
  for (int i = 0; i < (ROWS_PER_BLK * IN_F / 4) / 256; ++i)
    xl4[tid + i * 256] = x4[tid + i * 256];

  // detect drop_mask storage: 1-byte bool vs int32 (deterministic, data-based)
  if (tid < 64) {
    const unsigned char* m8 = (const unsigned char*)mask;
    unsigned long long b = __ballot(m8[tid] != 0);
    if (tid == 0) mask_is_u8 = (__popcll(b) > 32) ? 1 : 0;
  }
  __syncthreads();

  const int col = tid & 63;
  const int rg  = tid >> 6;  // 0..3, constant per wave

  float acc[8];
  #pragma unroll
  for (int i = 0; i < 8; ++i) acc[i] = 0.0f;

  #pragma unroll 4
  for (int k4 = 0; k4 < IN_F / 4; ++k4) {
    const float w0 = wlds[(4 * k4 + 0) * OUT_F + col];
    const float w1 = wlds[(4 * k4 + 1) * OUT_F + col];
    const float w2 = wlds[(4 * k4 + 2) * OUT_F + col];
    const float w3 = wlds[(4 * k4 + 3) * OUT_F + col];
    #pragma unroll
    for (int i = 0; i < 8; ++i) {
      const float4 xv = *(const float4*)&xlds[(rg + 4 * i) * IN_F + 4 * k4];
      acc[i] = fmaf(xv.x, w0,
               fmaf(xv.y, w1, fmaf(xv.z, w2, fmaf(xv.w, w3, acc[i]))));
    }
  }

  const float bv = bias[col];
  const unsigned char* m8 = (const unsigned char*)mask;
  const int* m32 = (const int*)mask;
  const int u8mode = mask_is_u8;

  #pragma unroll
  for (int i = 0; i < 8; ++i) {
    const int row = rowbase + rg + 4 * i;
    const size_t mi = (size_t)row * OUT_F + col;
    const int keep = u8mode ? (int)m8[mi] : m32[mi];
    const float v = keep ? (acc[i] + bv) * INV_KEEP : 0.0f;
    unsigned u = __float_as_uint(v);
    u += 0x7FFFu + ((u >> 16) & 1u);   // RNE f32->bf16
    hidden[mi] = (ushort)(u >> 16);
  }
}

// ---------------------------------------------------------------------------
// Kernel 2: bucket histogram (LDS-staged)
// ---------------------------------------------------------------------------
__global__ __launch_bounds__(256) void hist_kernel(
    const int* __restrict__ row_idx, int* __restrict__ cnt, int nedges) {
  __shared__ int hc[NB];
  const int t = threadIdx.x;
  for (int i = t; i < NB; i += 256) hc[i] = 0;
  __syncthreads();
  const int stride = gridDim.x * 256;
  for (int e = blockIdx.x * 256 + t; e < nedges; e += stride)
    atomicAdd(&hc[row_idx[e] >> RPB_LOG], 1);
  __syncthreads();
  for (int i = t; i < NB; i += 256)
    if (hc[i]) atomicAdd(&cnt[i], hc[i]);
}

// ---------------------------------------------------------------------------
// Kernel 3: one-block scan of NB counts -> base[NB+1], cursor[NB]
// ---------------------------------------------------------------------------
__global__ __launch_bounds__(1024) void scan_kernel(
    const int* __restrict__ cnt, int* __restrict__ base,
    int* __restrict__ cursor) {
  __shared__ int s[1024];
  const int t = threadIdx.x;
  const int v = (t < NB) ? cnt[t] : 0;
  s[t] = v;
  __syncthreads();
  int a = v;
  #pragma unroll
  for (int d = 1; d < 1024; d <<= 1) {
    const int add = (t >= d) ? s[t - d] : 0;
    __syncthreads();
    a += add;
    s[t] = a;
    __syncthreads();
  }
  if (t < NB) {
    base[t] = a - v;
    cursor[t] = a - v;
  }
  if (t == NB - 1) base[NB] = a;
}

// ---------------------------------------------------------------------------
// Kernel 4: bin — LDS counting-sort a 4096-edge chunk by bucket, then write
// coalesced runs into each bucket's reserved global range.
// meta = ((row & 127) << 17) | col   (24 bits), adj kept f32.
// ---------------------------------------------------------------------------
__global__ __launch_bounds__(BIN_BS) void bin_kernel(
    const int* __restrict__ row_idx, const int* __restrict__ col_idx,
    const float* __restrict__ adj, int* __restrict__ cursor,
    int2* __restrict__ packed, int nedges) {
  __shared__ unsigned sMeta[BIN_CHUNK];   // 16 KB
  __shared__ float    sAdj[BIN_CHUNK];    // 16 KB
  __shared__ ushort   sBkt[BIN_CHUNK];    //  8 KB
  __shared__ int      sCnt[1024];         //  4 KB
  __shared__ int      sScan[1024];        //  4 KB
  __shared__ int      sBase[1024];        //  4 KB
  __shared__ int      sFill[1024];        //  4 KB

  const int t = threadIdx.x;
  const int e0 = blockIdx.x * BIN_CHUNK;
  const int n = min(BIN_CHUNK, nedges - e0);

  sCnt[t] = 0;
  sBase[t] = 0;
  sFill[t] = 0;
  __syncthreads();

  int      eb[4];
  unsigned em[4];
  float    ea[4];
  #pragma unroll
  for (int j = 0; j < 4; ++j) {
    const int idx = t + j * BIN_BS;
    eb[j] = -1;
    if (idx < n) {
      const int r = row_idx[e0 + idx];
      const int c = col_idx[e0 + idx];
      ea[j] = adj[e0 + idx];
      eb[j] = r >> RPB_LOG;
      em[j] = ((unsigned)(r & (RPB - 1)) << 17) | (unsigned)c;
      atomicAdd(&sCnt[eb[j]], 1);
    }
  }
  __syncthreads();

  const int v = sCnt[t];
  sScan[t] = v;
  __syncthreads();
  int a = v;
  #pragma unroll
  for (int d = 1; d < 1024; d <<= 1) {
    const int add = (t >= d) ? sScan[t - d] : 0;
    __syncthreads();
    a += add;
    sScan[t] = a;
    __syncthreads();
  }
  const int excl = a - v;
  sScan[t] = excl;
  if (v > 0 && t < NB) sBase[t] = atomicAdd(&cursor[t], v);
  __syncthreads();

  #pragma unroll
  for (int j = 0; j < 4; ++j) {
    if (eb[j] >= 0) {
      const int p = sScan[eb[j]] + atomicAdd(&sFill[eb[j]], 1);
      sMeta[p] = em[j];
      sAdj[p] = ea[j];
      sBkt[p] = (ushort)eb[j];
    }
  }
  __syncthreads();

  #pragma unroll
  for (int j = 0; j < 4; ++j) {
    const int sp = t + j * BIN_BS;
    if (sp < n) {
      const int b = sBkt[sp];
      const int dst = sBase[b] + (sp - sScan[b]);
      int2 o;
      o.x = (int)sMeta[sp];
      o.y = __float_as_int(sAdj[sp]);
      packed[dst] = o;
    }
  }
}

// ---------------------------------------------------------------------------
// Kernel 5: bucket accumulate (REWRITTEN). 1024 threads = 16 waves/block;
// 2 blocks/CU (thread-limited) -> ~32 waves/CU. Each wave loads 64 edges
// coalesced (int2/lane), shfl-broadcasts in rounds of 8, keeps 8 bf16
// gathers in flight, ds-atomic-adds into the 32KB LDS tile. Fused ReLU store.
// ---------------------------------------------------------------------------
__global__ __launch_bounds__(ACC_BS) void bucket_acc_kernel(
    const int* __restrict__ base, const int2* __restrict__ packed,
    const ushort* __restrict__ hidden, float* __restrict__ out) {
  __shared__ float acc[RPB * OUT_F];  // 32 KB

  const int t = threadIdx.x;
  const int b = blockIdx.x;
  const int lane = t & 63;
  const int wv = t >> 6;  // 0..15

  float4* a4 = (float4*)acc;
  #pragma unroll
  for (int i = 0; i < (RPB * OUT_F / 4) / ACC_BS; ++i)   // 2
    a4[t + i * ACC_BS] = make_float4(0.f, 0.f, 0.f, 0.f);
  __syncthreads();

  const int s = base[b];
  const int e = base[b + 1];

  for (int g = s + wv * 64; g < e; g += 64 * ACC_NW) {
    const int cnt = min(64, e - g);
    int2 p = make_int2(0, 0);
    if (lane < cnt) p = packed[g + lane];  // 64 edges, coalesced 512B

    for (int j0 = 0; j0 < cnt; j0 += 8) {
      int   m[8];
      float av[8];
      #pragma unroll
      for (int j = 0; j < 8; ++j) {
        m[j] = __shfl(p.x, j0 + j);
        const int ai = __shfl(p.y, j0 + j);
        av[j] = (j0 + j < cnt) ? __int_as_float(ai) : 0.0f;
      }
      float h[8];
      #pragma unroll
      for (int j = 0; j < 8; ++j) {
        const int c = m[j] & 0x1FFFF;
        h[j] = __uint_as_float((unsigned)hidden[(size_t)c * OUT_F + lane] << 16);
      }
      #pragma unroll
      for (int j = 0; j < 8; ++j) {
        const int ro = (m[j] >> 17) & (RPB - 1);
        atomicAdd(&acc[ro * OUT_F + lane], av[j] * h[j]);
      }
    }
  }
  __syncthreads();

  const int rbase = b * RPB;
  float4* o4 = (float4*)(out + (size_t)rbase * OUT_F);
  #pragma unroll
  for (int i = 0; i < (RPB * OUT_F / 4) / ACC_BS; ++i) {  // 2
    const int idx4 = t + i * ACC_BS;
    const int r = idx4 >> 4;  // 16 float4 per row
    if (rbase + r < N_NODES) {
      float4 vv = a4[idx4];
      vv.x = fmaxf(vv.x, 0.f);
      vv.y = fmaxf(vv.y, 0.f);
      vv.z = fmaxf(vv.z, 0.f);
      vv.w = fmaxf(vv.w, 0.f);
      o4[idx4] = vv;
    }
  }
}

extern "C" void kernel_launch(void* const* d_in, const int* in_sizes, int n_in,
                              void* d_out, int out_size, void* d_ws,
                              size_t ws_size, hipStream_t stream) {
  const float* x       = (const float*)d_in[0];
  const int*   row_idx = (const int*)d_in[1];
  const int*   col_idx = (const int*)d_in[2];
  const float* adj     = (const float*)d_in[3];
  const void*  mask    = d_in[4];
  const float* w       = (const float*)d_in[5];
  const float* bias    = (const float*)d_in[6];
  float* out = (float*)d_out;
  const int nedges = in_sizes[1];

  // ws layout (16B-aligned): hidden bf16 | cnt | base | cursor | packed
  char* ws = (char*)d_ws;
  const size_t off_hidden = 0;
  const size_t sz_hidden  = (size_t)N_NODES * OUT_F * sizeof(ushort);  // 12.8MB
  const size_t off_cnt    = (off_hidden + sz_hidden + 15) & ~(size_t)15;
  const size_t off_base   = (off_cnt + NB * 4 + 15) & ~(size_t)15;
  const size_t off_cursor = (off_base + (NB + 1) * 4 + 15) & ~(size_t)15;
  const size_t off_packed = (off_cursor + NB * 4 + 15) & ~(size_t)15;

  ushort* hidden = (ushort*)(ws + off_hidden);
  int*    cnt    = (int*)(ws + off_cnt);
  int*    base   = (int*)(ws + off_base);
  int*    cursor = (int*)(ws + off_cursor);
  int2*   packed = (int2*)(ws + off_packed);

  gemm_dropout_kernel<<<N_NODES / ROWS_PER_BLK, 256, 0, stream>>>(
      x, w, bias, mask, hidden);

  hipMemsetAsync(cnt, 0, NB * 4, stream);
  hist_kernel<<<512, 256, 0, stream>>>(row_idx, cnt, nedges);
  scan_kernel<<<1, 1024, 0, stream>>>(cnt, base, cursor);
  bin_kernel<<<(nedges + BIN_CHUNK - 1) / BIN_CHUNK, BIN_BS, 0, stream>>>(
      row_idx, col_idx, adj, cursor, packed, nedges);
  bucket_acc_kernel<<<NB, ACC_BS, 0, stream>>>(base, packed, hidden, out);
}

// Round 6
// 152.087 us; speedup vs baseline: 5.2865x; 5.2865x over previous
//
#include <hip/hip_runtime.h>
#include <hip/hip_bf16.h>

#define N_NODES 100000
#define IN_F    128
#define OUT_F   64
#define ROWS_PER_BLK 32
#define INV_KEEP (1.0f / 0.9f)

#define RPB_LOG 7                 // rows per bucket = 128
#define RPB (1 << RPB_LOG)
#define NB  ((N_NODES + RPB - 1) / RPB)   // 782 buckets
#define BIN_CHUNK 4096
#define BIN_BS 1024
#define ACC_BS 1024
#define ACC_CHUNK 2560            // edges sorted per pass (avg bucket = 2046)

// ---------------------------------------------------------------------------
// Kernel 1: hidden = dropout(x @ W + b) -> bf16 [N_NODES x OUT_F] in ws.
// ---------------------------------------------------------------------------
__global__ __launch_bounds__(256) void gemm_dropout_kernel(
    const float* __restrict__ x, const float* __restrict__ w,
    const float* __restrict__ bias, const void* __restrict__ mask,
    ushort* __restrict__ hidden) {
  __shared__ float wlds[IN_F * OUT_F];          // 32 KB
  __shared__ float xlds[ROWS_PER_BLK * IN_F];   // 16 KB
  __shared__ int mask_is_u8;

  const int tid = threadIdx.x;
  const int rowbase = blockIdx.x * ROWS_PER_BLK;

  const float4* w4 = (const float4*)w;
  float4* wl4 = (float4*)wlds;
  #pragma unroll
  for (int i = 0; i < (IN_F * OUT_F / 4) / 256; ++i)
    wl4[tid + i * 256] = w4[tid + i * 256];

  const float4* x4 = (const float4*)(x + (size_t)rowbase * IN_F);
  float4* xl4 = (float4*)xlds;
  #pragma unroll
  for (int i = 0; i < (ROWS_PER_BLK * IN_F / 4) / 256; ++i)
    xl4[tid + i * 256] = x4[tid + i * 256];

  // detect drop_mask storage: 1-byte bool vs int32 (deterministic, data-based)
  if (tid < 64) {
    const unsigned char* m8 = (const unsigned char*)mask;
    unsigned long long b = __ballot(m8[tid] != 0);
    if (tid == 0) mask_is_u8 = (__popcll(b) > 32) ? 1 : 0;
  }
  __syncthreads();

  const int col = tid & 63;
  const int rg  = tid >> 6;  // 0..3, constant per wave

  float acc[8];
  #pragma unroll
  for (int i = 0; i < 8; ++i) acc[i] = 0.0f;

  #pragma unroll 4
  for (int k4 = 0; k4 < IN_F / 4; ++k4) {
    const float w0 = wlds[(4 * k4 + 0) * OUT_F + col];
    const float w1 = wlds[(4 * k4 + 1) * OUT_F + col];
    const float w2 = wlds[(4 * k4 + 2) * OUT_F + col];
    const float w3 = wlds[(4 * k4 + 3) * OUT_F + col];
    #pragma unroll
    for (int i = 0; i < 8; ++i) {
      const float4 xv = *(const float4*)&xlds[(rg + 4 * i) * IN_F + 4 * k4];
      acc[i] = fmaf(xv.x, w0,
               fmaf(xv.y, w1, fmaf(xv.z, w2, fmaf(xv.w, w3, acc[i]))));
    }
  }

  const float bv = bias[col];
  const unsigned char* m8 = (const unsigned char*)mask;
  const int* m32 = (const int*)mask;
  const int u8mode = mask_is_u8;

  #pragma unroll
  for (int i = 0; i < 8; ++i) {
    const int row = rowbase + rg + 4 * i;
    const size_t mi = (size_t)row * OUT_F + col;
    const int keep = u8mode ? (int)m8[mi] : m32[mi];
    const float v = keep ? (acc[i] + bv) * INV_KEEP : 0.0f;
    unsigned u = __float_as_uint(v);
    u += 0x7FFFu + ((u >> 16) & 1u);   // RNE f32->bf16
    hidden[mi] = (ushort)(u >> 16);
  }
}

// ---------------------------------------------------------------------------
// Kernel 2: bucket histogram (LDS-staged)
// ---------------------------------------------------------------------------
__global__ __launch_bounds__(256) void hist_kernel(
    const int* __restrict__ row_idx, int* __restrict__ cnt, int nedges) {
  __shared__ int hc[NB];
  const int t = threadIdx.x;
  for (int i = t; i < NB; i += 256) hc[i] = 0;
  __syncthreads();
  const int stride = gridDim.x * 256;
  for (int e = blockIdx.x * 256 + t; e < nedges; e += stride)
    atomicAdd(&hc[row_idx[e] >> RPB_LOG], 1);
  __syncthreads();
  for (int i = t; i < NB; i += 256)
    if (hc[i]) atomicAdd(&cnt[i], hc[i]);
}

// ---------------------------------------------------------------------------
// Kernel 3: one-block scan of NB counts -> base[NB+1], cursor[NB]
// ---------------------------------------------------------------------------
__global__ __launch_bounds__(1024) void scan_kernel(
    const int* __restrict__ cnt, int* __restrict__ base,
    int* __restrict__ cursor) {
  __shared__ int s[1024];
  const int t = threadIdx.x;
  const int v = (t < NB) ? cnt[t] : 0;
  s[t] = v;
  __syncthreads();
  int a = v;
  #pragma unroll
  for (int d = 1; d < 1024; d <<= 1) {
    const int add = (t >= d) ? s[t - d] : 0;
    __syncthreads();
    a += add;
    s[t] = a;
    __syncthreads();
  }
  if (t < NB) {
    base[t] = a - v;
    cursor[t] = a - v;
  }
  if (t == NB - 1) base[NB] = a;
}

// ---------------------------------------------------------------------------
// Kernel 4: bin — LDS counting-sort a 4096-edge chunk by bucket, then write
// coalesced runs into each bucket's reserved global range.
// meta = ((row & 127) << 17) | col   (24 bits), adj kept f32.
// ---------------------------------------------------------------------------
__global__ __launch_bounds__(BIN_BS) void bin_kernel(
    const int* __restrict__ row_idx, const int* __restrict__ col_idx,
    const float* __restrict__ adj, int* __restrict__ cursor,
    int2* __restrict__ packed, int nedges) {
  __shared__ unsigned sMeta[BIN_CHUNK];   // 16 KB
  __shared__ float    sAdj[BIN_CHUNK];    // 16 KB
  __shared__ ushort   sBkt[BIN_CHUNK];    //  8 KB
  __shared__ int      sCnt[1024];         //  4 KB
  __shared__ int      sScan[1024];        //  4 KB
  __shared__ int      sBase[1024];        //  4 KB
  __shared__ int      sFill[1024];        //  4 KB

  const int t = threadIdx.x;
  const int e0 = blockIdx.x * BIN_CHUNK;
  const int n = min(BIN_CHUNK, nedges - e0);

  sCnt[t] = 0;
  sBase[t] = 0;
  sFill[t] = 0;
  __syncthreads();

  int      eb[4];
  unsigned em[4];
  float    ea[4];
  #pragma unroll
  for (int j = 0; j < 4; ++j) {
    const int idx = t + j * BIN_BS;
    eb[j] = -1;
    if (idx < n) {
      const int r = row_idx[e0 + idx];
      const int c = col_idx[e0 + idx];
      ea[j] = adj[e0 + idx];
      eb[j] = r >> RPB_LOG;
      em[j] = ((unsigned)(r & (RPB - 1)) << 17) | (unsigned)c;
      atomicAdd(&sCnt[eb[j]], 1);
    }
  }
  __syncthreads();

  const int v = sCnt[t];
  sScan[t] = v;
  __syncthreads();
  int a = v;
  #pragma unroll
  for (int d = 1; d < 1024; d <<= 1) {
    const int add = (t >= d) ? sScan[t - d] : 0;
    __syncthreads();
    a += add;
    sScan[t] = a;
    __syncthreads();
  }
  const int excl = a - v;
  sScan[t] = excl;
  if (v > 0 && t < NB) sBase[t] = atomicAdd(&cursor[t], v);
  __syncthreads();

  #pragma unroll
  for (int j = 0; j < 4; ++j) {
    if (eb[j] >= 0) {
      const int p = sScan[eb[j]] + atomicAdd(&sFill[eb[j]], 1);
      sMeta[p] = em[j];
      sAdj[p] = ea[j];
      sBkt[p] = (ushort)eb[j];
    }
  }
  __syncthreads();

  #pragma unroll
  for (int j = 0; j < 4; ++j) {
    const int sp = t + j * BIN_BS;
    if (sp < n) {
      const int b = sBkt[sp];
      const int dst = sBase[b] + (sp - sScan[b]);
      int2 o;
      o.x = (int)sMeta[sp];
      o.y = __float_as_int(sAdj[sp]);
      packed[dst] = o;
    }
  }
}

// ---------------------------------------------------------------------------
// Kernel 5: bucket accumulate (NO f32 atomics). Per chunk of <=2560 edges:
// counting-sort by row-in-bucket in LDS (int atomics + 128-bin scan), then
// wave wv exclusively owns rows [wv*8, wv*8+8): reads (col,adj) as uniform
// LDS broadcasts, keeps 8 bf16 gathers in flight, accumulates in REGISTERS,
// one plain LDS add per row. Coalesced fused-ReLU tile store.
// ---------------------------------------------------------------------------
__global__ __launch_bounds__(ACC_BS) void bucket_acc_kernel(
    const int* __restrict__ base, const int2* __restrict__ packed,
    const ushort* __restrict__ hidden, float* __restrict__ out) {
  __shared__ float    accT[RPB * OUT_F];    // 32 KB
  __shared__ unsigned sMeta[ACC_CHUNK];     // 10 KB
  __shared__ float    sAdj[ACC_CHUNK];      // 10 KB
  __shared__ int      rowCnt[RPB];
  __shared__ int      rowOff[RPB + 1];
  __shared__ int      sTmp[RPB];

  const int t = threadIdx.x;
  const int b = blockIdx.x;
  const int lane = t & 63;
  const int wv = t >> 6;  // 0..15

  float4* a4 = (float4*)accT;
  #pragma unroll
  for (int i = 0; i < 2; ++i)
    a4[t + i * ACC_BS] = make_float4(0.f, 0.f, 0.f, 0.f);

  const int s = base[b];
  const int e = base[b + 1];

  for (int g0 = s; g0 < e; g0 += ACC_CHUNK) {
    const int n = min(ACC_CHUNK, e - g0);

    if (t < RPB) rowCnt[t] = 0;
    __syncthreads();

    // load up to 3 edges/thread, count rows (int LDS atomics: fast)
    unsigned m[3];
    float    a[3];
    int      ro[3], pos[3];
    #pragma unroll
    for (int j = 0; j < 3; ++j) {
      const int idx = t + j * ACC_BS;
      ro[j] = -1;
      if (idx < n) {
        const int2 p = packed[g0 + idx];   // coalesced
        m[j] = (unsigned)p.x;
        a[j] = __int_as_float(p.y);
        ro[j] = (int)((m[j] >> 17) & (RPB - 1));
        pos[j] = atomicAdd(&rowCnt[ro[j]], 1);
      }
    }
    __syncthreads();

    // exclusive scan of 128 row counts
    if (t < RPB) sTmp[t] = rowCnt[t];
    __syncthreads();
    for (int d = 1; d < RPB; d <<= 1) {
      int add = 0;
      if (t < RPB && t >= d) add = sTmp[t - d];
      __syncthreads();
      if (t < RPB) sTmp[t] += add;
      __syncthreads();
    }
    if (t < RPB) rowOff[t] = sTmp[t] - rowCnt[t];
    if (t == 0) rowOff[RPB] = n;
    __syncthreads();

    // scatter into row-sorted LDS positions
    #pragma unroll
    for (int j = 0; j < 3; ++j) {
      if (ro[j] >= 0) {
        const int p = rowOff[ro[j]] + pos[j];
        sMeta[p] = m[j];
        sAdj[p] = a[j];
      }
    }
    __syncthreads();

    // accumulate: wave wv owns rows wv*8 .. wv*8+7 (exclusive, no atomics)
    for (int r = wv * 8; r < wv * 8 + 8; ++r) {
      const int rs = rowOff[r];
      const int re = rowOff[r + 1];
      float acc = 0.0f;
      int i = rs;
      for (; i + 8 <= re; i += 8) {
        float h[8], av[8];
        #pragma unroll
        for (int j = 0; j < 8; ++j) {
          const unsigned mm = sMeta[i + j];   // uniform -> LDS broadcast
          av[j] = sAdj[i + j];
          const int c = (int)(mm & 0x1FFFFu);
          h[j] = __uint_as_float(
              (unsigned)hidden[(size_t)c * OUT_F + lane] << 16);
        }
        #pragma unroll
        for (int j = 0; j < 8; ++j) acc = fmaf(av[j], h[j], acc);
      }
      for (; i < re; ++i) {
        const unsigned mm = sMeta[i];
        const int c = (int)(mm & 0x1FFFFu);
        const float h = __uint_as_float(
            (unsigned)hidden[(size_t)c * OUT_F + lane] << 16);
        acc = fmaf(sAdj[i], h, acc);
      }
      if (acc != 0.0f || rs != re)
        accT[r * OUT_F + lane] += acc;  // plain LDS RMW, single owner
    }
    __syncthreads();  // chunk done before rowCnt/sMeta reuse
  }

  __syncthreads();
  const int rbase = b * RPB;
  float4* o4 = (float4*)(out + (size_t)rbase * OUT_F);
  #pragma unroll
  for (int i = 0; i < 2; ++i) {
    const int idx4 = t + i * ACC_BS;
    const int r = idx4 >> 4;  // 16 float4 per row
    if (rbase + r < N_NODES) {
      float4 vv = a4[idx4];
      vv.x = fmaxf(vv.x, 0.f);
      vv.y = fmaxf(vv.y, 0.f);
      vv.z = fmaxf(vv.z, 0.f);
      vv.w = fmaxf(vv.w, 0.f);
      o4[idx4] = vv;
    }
  }
}

extern "C" void kernel_launch(void* const* d_in, const int* in_sizes, int n_in,
                              void* d_out, int out_size, void* d_ws,
                              size_t ws_size, hipStream_t stream) {
  const float* x       = (const float*)d_in[0];
  const int*   row_idx = (const int*)d_in[1];
  const int*   col_idx = (const int*)d_in[2];
  const float* adj     = (const float*)d_in[3];
  const void*  mask    = d_in[4];
  const float* w       = (const float*)d_in[5];
  const float* bias    = (const float*)d_in[6];
  float* out = (float*)d_out;
  const int nedges = in_sizes[1];

  // ws layout (16B-aligned): hidden bf16 | cnt | base | cursor | packed
  char* ws = (char*)d_ws;
  const size_t off_hidden = 0;
  const size_t sz_hidden  = (size_t)N_NODES * OUT_F * sizeof(ushort);  // 12.8MB
  const size_t off_cnt    = (off_hidden + sz_hidden + 15) & ~(size_t)15;
  const size_t off_base   = (off_cnt + NB * 4 + 15) & ~(size_t)15;
  const size_t off_cursor = (off_base + (NB + 1) * 4 + 15) & ~(size_t)15;
  const size_t off_packed = (off_cursor + NB * 4 + 15) & ~(size_t)15;

  ushort* hidden = (ushort*)(ws + off_hidden);
  int*    cnt    = (int*)(ws + off_cnt);
  int*    base   = (int*)(ws + off_base);
  int*    cursor = (int*)(ws + off_cursor);
  int2*   packed = (int2*)(ws + off_packed);

  gemm_dropout_kernel<<<N_NODES / ROWS_PER_BLK, 256, 0, stream>>>(
      x, w, bias, mask, hidden);

  hipMemsetAsync(cnt, 0, NB * 4, stream);
  hist_kernel<<<512, 256, 0, stream>>>(row_idx, cnt, nedges);
  scan_kernel<<<1, 1024, 0, stream>>>(cnt, base, cursor);
  bin_kernel<<<(nedges + BIN_CHUNK - 1) / BIN_CHUNK, BIN_BS, 0, stream>>>(
      row_idx, col_idx, adj, cursor, packed, nedges);
  bucket_acc_kernel<<<NB, ACC_BS, 0, stream>>>(base, packed, hidden, out);
}

// Round 7
// 148.565 us; speedup vs baseline: 5.4118x; 1.0237x over previous
//
#include <hip/hip_runtime.h>
#include <hip/hip_bf16.h>

#define N_NODES 100000
#define IN_F    128
#define OUT_F   64
#define INV_KEEP (1.0f / 0.9f)

#define RPB_LOG 7                 // rows per bucket = 128
#define RPB (1 << RPB_LOG)
#define NB  ((N_NODES + RPB - 1) / RPB)   // 782 buckets
#define BIN_CHUNK 4096
#define BIN_BS 1024
#define ACC_BS 1024
#define ACC_CHUNK 2560            // edges sorted per pass (avg bucket = 2046)

#define G_ROWS 256                // rows per gemm block
#define XS 260                    // xlds per-k row stride (floats); 16B-aligned, odd/16 spread

// ---------------------------------------------------------------------------
// Kernel 1: hidden = dropout(x @ W + b) -> bf16. Register-tiled: thread owns
// 4 rows x 16 cols. x chunk staged k-major (xlds[k][row], stride 260 -> 2-way
// banks = free). Per k: 1 x-b128 + 4 w-b128 per 64 FMA; LDS traffic 3.7GB->1GB.
// ---------------------------------------------------------------------------
__global__ __launch_bounds__(256) void gemm_dropout_kernel(
    const float* __restrict__ x, const float* __restrict__ w,
    const float* __restrict__ bias, const void* __restrict__ mask,
    ushort* __restrict__ hidden) {
  __shared__ float wlds[IN_F * OUT_F];   // 32 KB, row-major [k][64]
  __shared__ float xlds[16 * XS];        // 16.25 KB, [k- within chunk][row]
  __shared__ int mask_is_u8;

  const int tid = threadIdx.x;
  const int rowbase = blockIdx.x * G_ROWS;

  // stage W (8192 floats, 8 float4/thread)
  const float4* w4 = (const float4*)w;
  float4* wl4 = (float4*)wlds;
  #pragma unroll
  for (int i = 0; i < 8; ++i)
    wl4[tid + i * 256] = w4[tid + i * 256];

  // detect drop_mask storage: 1-byte bool vs int32 (deterministic, data-based)
  if (tid < 64) {
    const unsigned char* m8 = (const unsigned char*)mask;
    unsigned long long b = __ballot(m8[tid] != 0);
    if (tid == 0) mask_is_u8 = (__popcll(b) > 32) ? 1 : 0;
  }

  const int j  = tid & 3;          // col group: cols 16j..16j+15
  const int i4 = tid >> 2;         // row group: local rows 4*i4..4*i4+3
  const int r0 = 4 * i4;
  const int c0 = 16 * j;

  const float4 bv0 = *(const float4*)&bias[c0 + 0];
  const float4 bv1 = *(const float4*)&bias[c0 + 4];
  const float4 bv2 = *(const float4*)&bias[c0 + 8];
  const float4 bv3 = *(const float4*)&bias[c0 + 12];

  float4 acc[4][4];  // [row][col-quad]
  #pragma unroll
  for (int r = 0; r < 4; ++r)
    #pragma unroll
    for (int q = 0; q < 4; ++q) acc[r][q] = make_float4(0.f, 0.f, 0.f, 0.f);

  __syncthreads();  // W staged + mask flag visible

  for (int k0 = 0; k0 < IN_F; k0 += 16) {
    // stage x[rowbase+tid][k0..k0+15] -> xlds[kk][tid] (k-major)
    const int gr = rowbase + tid;
    if (gr < N_NODES) {
      const float4* src = (const float4*)(x + (size_t)gr * IN_F + k0);
      #pragma unroll
      for (int q = 0; q < 4; ++q) {
        const float4 v = src[q];
        xlds[(4 * q + 0) * XS + tid] = v.x;
        xlds[(4 * q + 1) * XS + tid] = v.y;
        xlds[(4 * q + 2) * XS + tid] = v.z;
        xlds[(4 * q + 3) * XS + tid] = v.w;
      }
    }
    __syncthreads();

    #pragma unroll
    for (int kk = 0; kk < 16; ++kk) {
      const float4 xv = *(const float4*)&xlds[kk * XS + r0];  // 4 rows @ k
      float4 wv[4];
      #pragma unroll
      for (int q = 0; q < 4; ++q)
        wv[q] = *(const float4*)&wlds[(k0 + kk) * OUT_F + c0 + 4 * q];
#define FMA4(A, s, B) \
  A.x = fmaf(s, B.x, A.x); A.y = fmaf(s, B.y, A.y); \
  A.z = fmaf(s, B.z, A.z); A.w = fmaf(s, B.w, A.w)
      #pragma unroll
      for (int q = 0; q < 4; ++q) {
        FMA4(acc[0][q], xv.x, wv[q]);
        FMA4(acc[1][q], xv.y, wv[q]);
        FMA4(acc[2][q], xv.z, wv[q]);
        FMA4(acc[3][q], xv.w, wv[q]);
      }
#undef FMA4
    }
    __syncthreads();
  }

  // epilogue: bias + dropout + bf16 RNE + packed store
  const unsigned char* m8 = (const unsigned char*)mask;
  const int* m32 = (const int*)mask;
  const int u8mode = mask_is_u8;

  #pragma unroll
  for (int r = 0; r < 4; ++r) {
    const int grow = rowbase + r0 + r;
    if (grow < N_NODES) {
      const size_t mbase = (size_t)grow * OUT_F + c0;
      unsigned keep[16];
      if (u8mode) {
        const uint4 mv = *(const uint4*)(m8 + mbase);  // 16 bytes, aligned
        #pragma unroll
        for (int b = 0; b < 4; ++b) {
          keep[0 + b]  = (mv.x >> (8 * b)) & 255u;
          keep[4 + b]  = (mv.y >> (8 * b)) & 255u;
          keep[8 + b]  = (mv.z >> (8 * b)) & 255u;
          keep[12 + b] = (mv.w >> (8 * b)) & 255u;
        }
      } else {
        #pragma unroll
        for (int q = 0; q < 4; ++q) {
          const int4 mv = *(const int4*)(m32 + mbase + 4 * q);
          keep[4 * q + 0] = (unsigned)mv.x;
          keep[4 * q + 1] = (unsigned)mv.y;
          keep[4 * q + 2] = (unsigned)mv.z;
          keep[4 * q + 3] = (unsigned)mv.w;
        }
      }
      float vals[16];
      #pragma unroll
      for (int q = 0; q < 4; ++q) {
        const float4 a = acc[r][q];
        const float4 bb = (q == 0) ? bv0 : (q == 1) ? bv1 : (q == 2) ? bv2 : bv3;
        vals[4 * q + 0] = a.x + bb.x;
        vals[4 * q + 1] = a.y + bb.y;
        vals[4 * q + 2] = a.z + bb.z;
        vals[4 * q + 3] = a.w + bb.w;
      }
      unsigned hw[8];
      #pragma unroll
      for (int p = 0; p < 8; ++p) {
        float v0 = keep[2 * p]     ? vals[2 * p] * INV_KEEP     : 0.f;
        float v1 = keep[2 * p + 1] ? vals[2 * p + 1] * INV_KEEP : 0.f;
        unsigned u0 = __float_as_uint(v0);
        u0 += 0x7FFFu + ((u0 >> 16) & 1u);
        unsigned u1 = __float_as_uint(v1);
        u1 += 0x7FFFu + ((u1 >> 16) & 1u);
        hw[p] = (u0 >> 16) | (u1 & 0xFFFF0000u);
      }
      uint4* dst = (uint4*)&hidden[mbase];
      dst[0] = make_uint4(hw[0], hw[1], hw[2], hw[3]);
      dst[1] = make_uint4(hw[4], hw[5], hw[6], hw[7]);
    }
  }
}

// ---------------------------------------------------------------------------
// Kernel 2: bucket histogram (LDS-staged)
// ---------------------------------------------------------------------------
__global__ __launch_bounds__(256) void hist_kernel(
    const int* __restrict__ row_idx, int* __restrict__ cnt, int nedges) {
  __shared__ int hc[NB];
  const int t = threadIdx.x;
  for (int i = t; i < NB; i += 256) hc[i] = 0;
  __syncthreads();
  const int stride = gridDim.x * 256;
  for (int e = blockIdx.x * 256 + t; e < nedges; e += stride)
    atomicAdd(&hc[row_idx[e] >> RPB_LOG], 1);
  __syncthreads();
  for (int i = t; i < NB; i += 256)
    if (hc[i]) atomicAdd(&cnt[i], hc[i]);
}

// ---------------------------------------------------------------------------
// Kernel 3: one-block scan of NB counts -> base[NB+1], cursor[NB]
// ---------------------------------------------------------------------------
__global__ __launch_bounds__(1024) void scan_kernel(
    const int* __restrict__ cnt, int* __restrict__ base,
    int* __restrict__ cursor) {
  __shared__ int s[1024];
  const int t = threadIdx.x;
  const int v = (t < NB) ? cnt[t] : 0;
  s[t] = v;
  __syncthreads();
  int a = v;
  #pragma unroll
  for (int d = 1; d < 1024; d <<= 1) {
    const int add = (t >= d) ? s[t - d] : 0;
    __syncthreads();
    a += add;
    s[t] = a;
    __syncthreads();
  }
  if (t < NB) {
    base[t] = a - v;
    cursor[t] = a - v;
  }
  if (t == NB - 1) base[NB] = a;
}

// ---------------------------------------------------------------------------
// Kernel 4: bin — LDS counting-sort a 4096-edge chunk by bucket, then write
// coalesced runs into each bucket's reserved global range.
// meta = ((row & 127) << 17) | col   (24 bits), adj kept f32.
// ---------------------------------------------------------------------------
__global__ __launch_bounds__(BIN_BS) void bin_kernel(
    const int* __restrict__ row_idx, const int* __restrict__ col_idx,
    const float* __restrict__ adj, int* __restrict__ cursor,
    int2* __restrict__ packed, int nedges) {
  __shared__ unsigned sMeta[BIN_CHUNK];   // 16 KB
  __shared__ float    sAdj[BIN_CHUNK];    // 16 KB
  __shared__ ushort   sBkt[BIN_CHUNK];    //  8 KB
  __shared__ int      sCnt[1024];         //  4 KB
  __shared__ int      sScan[1024];        //  4 KB
  __shared__ int      sBase[1024];        //  4 KB
  __shared__ int      sFill[1024];        //  4 KB

  const int t = threadIdx.x;
  const int e0 = blockIdx.x * BIN_CHUNK;
  const int n = min(BIN_CHUNK, nedges - e0);

  sCnt[t] = 0;
  sBase[t] = 0;
  sFill[t] = 0;
  __syncthreads();

  int      eb[4];
  unsigned em[4];
  float    ea[4];
  #pragma unroll
  for (int j = 0; j < 4; ++j) {
    const int idx = t + j * BIN_BS;
    eb[j] = -1;
    if (idx < n) {
      const int r = row_idx[e0 + idx];
      const int c = col_idx[e0 + idx];
      ea[j] = adj[e0 + idx];
      eb[j] = r >> RPB_LOG;
      em[j] = ((unsigned)(r & (RPB - 1)) << 17) | (unsigned)c;
      atomicAdd(&sCnt[eb[j]], 1);
    }
  }
  __syncthreads();

  const int v = sCnt[t];
  sScan[t] = v;
  __syncthreads();
  int a = v;
  #pragma unroll
  for (int d = 1; d < 1024; d <<= 1) {
    const int add = (t >= d) ? sScan[t - d] : 0;
    __syncthreads();
    a += add;
    sScan[t] = a;
    __syncthreads();
  }
  const int excl = a - v;
  sScan[t] = excl;
  if (v > 0 && t < NB) sBase[t] = atomicAdd(&cursor[t], v);
  __syncthreads();

  #pragma unroll
  for (int j = 0; j < 4; ++j) {
    if (eb[j] >= 0) {
      const int p = sScan[eb[j]] + atomicAdd(&sFill[eb[j]], 1);
      sMeta[p] = em[j];
      sAdj[p] = ea[j];
      sBkt[p] = (ushort)eb[j];
    }
  }
  __syncthreads();

  #pragma unroll
  for (int j = 0; j < 4; ++j) {
    const int sp = t + j * BIN_BS;
    if (sp < n) {
      const int b = sBkt[sp];
      const int dst = sBase[b] + (sp - sScan[b]);
      int2 o;
      o.x = (int)sMeta[sp];
      o.y = __float_as_int(sAdj[sp]);
      packed[dst] = o;
    }
  }
}

// ---------------------------------------------------------------------------
// Kernel 5: bucket accumulate (NO f32 atomics). Per chunk of <=2560 edges:
// counting-sort by row-in-bucket in LDS (int atomics + 128-bin scan), then
// wave wv exclusively owns rows [wv*8, wv*8+8): reads (col,adj) as uniform
// LDS broadcasts, keeps 8 bf16 gathers in flight, accumulates in REGISTERS,
// one plain LDS add per row. Coalesced fused-ReLU tile store.
// ---------------------------------------------------------------------------
__global__ __launch_bounds__(ACC_BS) void bucket_acc_kernel(
    const int* __restrict__ base, const int2* __restrict__ packed,
    const ushort* __restrict__ hidden, float* __restrict__ out) {
  __shared__ float    accT[RPB * OUT_F];    // 32 KB
  __shared__ unsigned sMeta[ACC_CHUNK];     // 10 KB
  __shared__ float    sAdj[ACC_CHUNK];      // 10 KB
  __shared__ int      rowCnt[RPB];
  __shared__ int      rowOff[RPB + 1];
  __shared__ int      sTmp[RPB];

  const int t = threadIdx.x;
  const int b = blockIdx.x;
  const int lane = t & 63;
  const int wv = t >> 6;  // 0..15

  float4* a4 = (float4*)accT;
  #pragma unroll
  for (int i = 0; i < 2; ++i)
    a4[t + i * ACC_BS] = make_float4(0.f, 0.f, 0.f, 0.f);

  const int s = base[b];
  const int e = base[b + 1];

  for (int g0 = s; g0 < e; g0 += ACC_CHUNK) {
    const int n = min(ACC_CHUNK, e - g0);

    if (t < RPB) rowCnt[t] = 0;
    __syncthreads();

    unsigned m[3];
    float    a[3];
    int      ro[3], pos[3];
    #pragma unroll
    for (int j = 0; j < 3; ++j) {
      const int idx = t + j * ACC_BS;
      ro[j] = -1;
      if (idx < n) {
        const int2 p = packed[g0 + idx];   // coalesced
        m[j] = (unsigned)p.x;
        a[j] = __int_as_float(p.y);
        ro[j] = (int)((m[j] >> 17) & (RPB - 1));
        pos[j] = atomicAdd(&rowCnt[ro[j]], 1);
      }
    }
    __syncthreads();

    if (t < RPB) sTmp[t] = rowCnt[t];
    __syncthreads();
    for (int d = 1; d < RPB; d <<= 1) {
      int add = 0;
      if (t < RPB && t >= d) add = sTmp[t - d];
      __syncthreads();
      if (t < RPB) sTmp[t] += add;
      __syncthreads();
    }
    if (t < RPB) rowOff[t] = sTmp[t] - rowCnt[t];
    if (t == 0) rowOff[RPB] = n;
    __syncthreads();

    #pragma unroll
    for (int j = 0; j < 3; ++j) {
      if (ro[j] >= 0) {
        const int p = rowOff[ro[j]] + pos[j];
        sMeta[p] = m[j];
        sAdj[p] = a[j];
      }
    }
    __syncthreads();

    for (int r = wv * 8; r < wv * 8 + 8; ++r) {
      const int rs = rowOff[r];
      const int re = rowOff[r + 1];
      float acc = 0.0f;
      int i = rs;
      for (; i + 8 <= re; i += 8) {
        float h[8], av[8];
        #pragma unroll
        for (int j = 0; j < 8; ++j) {
          const unsigned mm = sMeta[i + j];   // uniform -> LDS broadcast
          av[j] = sAdj[i + j];
          const int c = (int)(mm & 0x1FFFFu);
          h[j] = __uint_as_float(
              (unsigned)hidden[(size_t)c * OUT_F + lane] << 16);
        }
        #pragma unroll
        for (int j = 0; j < 8; ++j) acc = fmaf(av[j], h[j], acc);
      }
      for (; i < re; ++i) {
        const unsigned mm = sMeta[i];
        const int c = (int)(mm & 0x1FFFFu);
        const float h = __uint_as_float(
            (unsigned)hidden[(size_t)c * OUT_F + lane] << 16);
        acc = fmaf(sAdj[i], h, acc);
      }
      if (acc != 0.0f || rs != re)
        accT[r * OUT_F + lane] += acc;  // plain LDS RMW, single owner
    }
    __syncthreads();  // chunk done before rowCnt/sMeta reuse
  }

  __syncthreads();
  const int rbase = b * RPB;
  float4* o4 = (float4*)(out + (size_t)rbase * OUT_F);
  #pragma unroll
  for (int i = 0; i < 2; ++i) {
    const int idx4 = t + i * ACC_BS;
    const int r = idx4 >> 4;  // 16 float4 per row
    if (rbase + r < N_NODES) {
      float4 vv = a4[idx4];
      vv.x = fmaxf(vv.x, 0.f);
      vv.y = fmaxf(vv.y, 0.f);
      vv.z = fmaxf(vv.z, 0.f);
      vv.w = fmaxf(vv.w, 0.f);
      o4[idx4] = vv;
    }
  }
}

extern "C" void kernel_launch(void* const* d_in, const int* in_sizes, int n_in,
                              void* d_out, int out_size, void* d_ws,
                              size_t ws_size, hipStream_t stream) {
  const float* x       = (const float*)d_in[0];
  const int*   row_idx = (const int*)d_in[1];
  const int*   col_idx = (const int*)d_in[2];
  const float* adj     = (const float*)d_in[3];
  const void*  mask    = d_in[4];
  const float* w       = (const float*)d_in[5];
  const float* bias    = (const float*)d_in[6];
  float* out = (float*)d_out;
  const int nedges = in_sizes[1];

  // ws layout (16B-aligned): hidden bf16 | cnt | base | cursor | packed
  char* ws = (char*)d_ws;
  const size_t off_hidden = 0;
  const size_t sz_hidden  = (size_t)N_NODES * OUT_F * sizeof(ushort);  // 12.8MB
  const size_t off_cnt    = (off_hidden + sz_hidden + 15) & ~(size_t)15;
  const size_t off_base   = (off_cnt + NB * 4 + 15) & ~(size_t)15;
  const size_t off_cursor = (off_base + (NB + 1) * 4 + 15) & ~(size_t)15;
  const size_t off_packed = (off_cursor + NB * 4 + 15) & ~(size_t)15;

  ushort* hidden = (ushort*)(ws + off_hidden);
  int*    cnt    = (int*)(ws + off_cnt);
  int*    base   = (int*)(ws + off_base);
  int*    cursor = (int*)(ws + off_cursor);
  int2*   packed = (int2*)(ws + off_packed);

  gemm_dropout_kernel<<<(N_NODES + G_ROWS - 1) / G_ROWS, 256, 0, stream>>>(
      x, w, bias, mask, hidden);

  hipMemsetAsync(cnt, 0, NB * 4, stream);
  hist_kernel<<<512, 256, 0, stream>>>(row_idx, cnt, nedges);
  scan_kernel<<<1, 1024, 0, stream>>>(cnt, base, cursor);
  bin_kernel<<<(nedges + BIN_CHUNK - 1) / BIN_CHUNK, BIN_BS, 0, stream>>>(
      row_idx, col_idx, adj, cursor, packed, nedges);
  bucket_acc_kernel<<<NB, ACC_BS, 0, stream>>>(base, packed, hidden, out);
}

// Round 8
// 128.221 us; speedup vs baseline: 6.2705x; 1.1587x over previous
//
#include <hip/hip_runtime.h>
#include <hip/hip_bf16.h>

#define N_NODES 100000
#define IN_F    128
#define OUT_F   64
#define INV_KEEP (1.0f / 0.9f)

#define RPB_LOG 7                 // rows per bucket = 128
#define RPB (1 << RPB_LOG)
#define NB  ((N_NODES + RPB - 1) / RPB)   // 782 buckets
#define BIN_CHUNK 4096
#define BIN_BS 1024
#define ACC_BS 1024
#define ACC_CHUNK 2560            // edges sorted per pass (avg bucket = 2046)

#define G_BS   128                // gemm block threads
#define G_ROWS 128                // rows per gemm block -> grid 782

// ---------------------------------------------------------------------------
// Kernel 1: hidden = dropout(x @ W + b) -> bf16. Thread owns 4 rows x 16 cols.
// x: direct global->reg float4, software-pipelined, NO barriers in k-loop.
// W: 32 KB LDS, b128 wave-broadcast reads (4 distinct addrs/wave ~ free).
// 128-thread blocks, grid 782 (3 blocks/CU resident, balanced).
// ---------------------------------------------------------------------------
__global__ __launch_bounds__(G_BS) void gemm_dropout_kernel(
    const float* __restrict__ x, const float* __restrict__ w,
    const float* __restrict__ bias, const void* __restrict__ mask,
    ushort* __restrict__ hidden) {
  __shared__ float wlds[IN_F * OUT_F];   // 32 KB, row-major [k][64]
  __shared__ int mask_is_u8;

  const int tid = threadIdx.x;
  const int rowbase = blockIdx.x * G_ROWS;

  // stage W (8192 floats, 16 float4/thread, coalesced)
  const float4* w4 = (const float4*)w;
  float4* wl4 = (float4*)wlds;
  #pragma unroll
  for (int i = 0; i < 16; ++i)
    wl4[tid + i * G_BS] = w4[tid + i * G_BS];

  // detect drop_mask storage: 1-byte bool vs int32 (deterministic, data-based)
  if (tid < 64) {
    const unsigned char* m8 = (const unsigned char*)mask;
    unsigned long long b = __ballot(m8[tid] != 0);
    if (tid == 0) mask_is_u8 = (__popcll(b) > 32) ? 1 : 0;
  }

  const int j  = tid & 3;          // col group: cols 16j..16j+15
  const int i4 = tid >> 2;         // 0..31
  const int r0 = 4 * i4;           // local row base
  const int c0 = 16 * j;

  const float4 bv0 = *(const float4*)&bias[c0 + 0];
  const float4 bv1 = *(const float4*)&bias[c0 + 4];
  const float4 bv2 = *(const float4*)&bias[c0 + 8];
  const float4 bv3 = *(const float4*)&bias[c0 + 12];

  float4 acc[4][4];  // [row][col-quad]
  #pragma unroll
  for (int r = 0; r < 4; ++r)
    #pragma unroll
    for (int q = 0; q < 4; ++q) acc[r][q] = make_float4(0.f, 0.f, 0.f, 0.f);

  // clamped x row pointers (branchless OOB handling; stores are guarded)
  const float* xp[4];
  #pragma unroll
  for (int r = 0; r < 4; ++r) {
    int grow = rowbase + r0 + r;
    grow = (grow < N_NODES) ? grow : (N_NODES - 1);
    xp[r] = x + (size_t)grow * IN_F;
  }

  __syncthreads();  // W staged + mask flag visible

  float4 xq[4];
  #pragma unroll
  for (int r = 0; r < 4; ++r) xq[r] = *(const float4*)(xp[r]);

#define FMA4(A, s, B) \
  A.x = fmaf(s, B.x, A.x); A.y = fmaf(s, B.y, A.y); \
  A.z = fmaf(s, B.z, A.z); A.w = fmaf(s, B.w, A.w)

  #pragma unroll 2
  for (int k0 = 0; k0 < IN_F; k0 += 4) {
    float4 xn[4];
    if (k0 + 4 < IN_F) {
      #pragma unroll
      for (int r = 0; r < 4; ++r)
        xn[r] = *(const float4*)(xp[r] + k0 + 4);
    }
    #pragma unroll
    for (int kk = 0; kk < 4; ++kk) {
      float4 wv[4];
      #pragma unroll
      for (int q = 0; q < 4; ++q)
        wv[q] = *(const float4*)&wlds[(k0 + kk) * OUT_F + c0 + 4 * q];
      const float x0 = (kk == 0) ? xq[0].x : (kk == 1) ? xq[0].y : (kk == 2) ? xq[0].z : xq[0].w;
      const float x1 = (kk == 0) ? xq[1].x : (kk == 1) ? xq[1].y : (kk == 2) ? xq[1].z : xq[1].w;
      const float x2 = (kk == 0) ? xq[2].x : (kk == 1) ? xq[2].y : (kk == 2) ? xq[2].z : xq[2].w;
      const float x3 = (kk == 0) ? xq[3].x : (kk == 1) ? xq[3].y : (kk == 2) ? xq[3].z : xq[3].w;
      #pragma unroll
      for (int q = 0; q < 4; ++q) {
        FMA4(acc[0][q], x0, wv[q]);
        FMA4(acc[1][q], x1, wv[q]);
        FMA4(acc[2][q], x2, wv[q]);
        FMA4(acc[3][q], x3, wv[q]);
      }
    }
    if (k0 + 4 < IN_F) {
      #pragma unroll
      for (int r = 0; r < 4; ++r) xq[r] = xn[r];
    }
  }
#undef FMA4

  // epilogue: bias + dropout + bf16 RNE + packed store
  const unsigned char* m8 = (const unsigned char*)mask;
  const int* m32 = (const int*)mask;
  const int u8mode = mask_is_u8;

  #pragma unroll
  for (int r = 0; r < 4; ++r) {
    const int grow = rowbase + r0 + r;
    if (grow < N_NODES) {
      const size_t mbase = (size_t)grow * OUT_F + c0;
      unsigned keep[16];
      if (u8mode) {
        const uint4 mv = *(const uint4*)(m8 + mbase);  // 16 bytes, aligned
        #pragma unroll
        for (int b = 0; b < 4; ++b) {
          keep[0 + b]  = (mv.x >> (8 * b)) & 255u;
          keep[4 + b]  = (mv.y >> (8 * b)) & 255u;
          keep[8 + b]  = (mv.z >> (8 * b)) & 255u;
          keep[12 + b] = (mv.w >> (8 * b)) & 255u;
        }
      } else {
        #pragma unroll
        for (int q = 0; q < 4; ++q) {
          const int4 mv = *(const int4*)(m32 + mbase + 4 * q);
          keep[4 * q + 0] = (unsigned)mv.x;
          keep[4 * q + 1] = (unsigned)mv.y;
          keep[4 * q + 2] = (unsigned)mv.z;
          keep[4 * q + 3] = (unsigned)mv.w;
        }
      }
      float vals[16];
      #pragma unroll
      for (int q = 0; q < 4; ++q) {
        const float4 a = acc[r][q];
        const float4 bb = (q == 0) ? bv0 : (q == 1) ? bv1 : (q == 2) ? bv2 : bv3;
        vals[4 * q + 0] = a.x + bb.x;
        vals[4 * q + 1] = a.y + bb.y;
        vals[4 * q + 2] = a.z + bb.z;
        vals[4 * q + 3] = a.w + bb.w;
      }
      unsigned hw[8];
      #pragma unroll
      for (int p = 0; p < 8; ++p) {
        float v0 = keep[2 * p]     ? vals[2 * p] * INV_KEEP     : 0.f;
        float v1 = keep[2 * p + 1] ? vals[2 * p + 1] * INV_KEEP : 0.f;
        unsigned u0 = __float_as_uint(v0);
        u0 += 0x7FFFu + ((u0 >> 16) & 1u);
        unsigned u1 = __float_as_uint(v1);
        u1 += 0x7FFFu + ((u1 >> 16) & 1u);
        hw[p] = (u0 >> 16) | (u1 & 0xFFFF0000u);
      }
      uint4* dst = (uint4*)&hidden[mbase];
      dst[0] = make_uint4(hw[0], hw[1], hw[2], hw[3]);
      dst[1] = make_uint4(hw[4], hw[5], hw[6], hw[7]);
    }
  }
}

// ---------------------------------------------------------------------------
// Kernel 2: bucket histogram (LDS-staged)
// ---------------------------------------------------------------------------
__global__ __launch_bounds__(256) void hist_kernel(
    const int* __restrict__ row_idx, int* __restrict__ cnt, int nedges) {
  __shared__ int hc[NB];
  const int t = threadIdx.x;
  for (int i = t; i < NB; i += 256) hc[i] = 0;
  __syncthreads();
  const int stride = gridDim.x * 256;
  for (int e = blockIdx.x * 256 + t; e < nedges; e += stride)
    atomicAdd(&hc[row_idx[e] >> RPB_LOG], 1);
  __syncthreads();
  for (int i = t; i < NB; i += 256)
    if (hc[i]) atomicAdd(&cnt[i], hc[i]);
}

// ---------------------------------------------------------------------------
// Kernel 3: one-block scan of NB counts -> base[NB+1], cursor[NB]
// ---------------------------------------------------------------------------
__global__ __launch_bounds__(1024) void scan_kernel(
    const int* __restrict__ cnt, int* __restrict__ base,
    int* __restrict__ cursor) {
  __shared__ int s[1024];
  const int t = threadIdx.x;
  const int v = (t < NB) ? cnt[t] : 0;
  s[t] = v;
  __syncthreads();
  int a = v;
  #pragma unroll
  for (int d = 1; d < 1024; d <<= 1) {
    const int add = (t >= d) ? s[t - d] : 0;
    __syncthreads();
    a += add;
    s[t] = a;
    __syncthreads();
  }
  if (t < NB) {
    base[t] = a - v;
    cursor[t] = a - v;
  }
  if (t == NB - 1) base[NB] = a;
}

// ---------------------------------------------------------------------------
// Kernel 4: bin — LDS counting-sort a 4096-edge chunk by bucket, then write
// coalesced runs into each bucket's reserved global range.
// meta = ((row & 127) << 17) | col   (24 bits), adj kept f32.
// ---------------------------------------------------------------------------
__global__ __launch_bounds__(BIN_BS) void bin_kernel(
    const int* __restrict__ row_idx, const int* __restrict__ col_idx,
    const float* __restrict__ adj, int* __restrict__ cursor,
    int2* __restrict__ packed, int nedges) {
  __shared__ unsigned sMeta[BIN_CHUNK];   // 16 KB
  __shared__ float    sAdj[BIN_CHUNK];    // 16 KB
  __shared__ ushort   sBkt[BIN_CHUNK];    //  8 KB
  __shared__ int      sCnt[1024];         //  4 KB
  __shared__ int      sScan[1024];        //  4 KB
  __shared__ int      sBase[1024];        //  4 KB
  __shared__ int      sFill[1024];        //  4 KB

  const int t = threadIdx.x;
  const int e0 = blockIdx.x * BIN_CHUNK;
  const int n = min(BIN_CHUNK, nedges - e0);

  sCnt[t] = 0;
  sBase[t] = 0;
  sFill[t] = 0;
  __syncthreads();

  int      eb[4];
  unsigned em[4];
  float    ea[4];
  #pragma unroll
  for (int j = 0; j < 4; ++j) {
    const int idx = t + j * BIN_BS;
    eb[j] = -1;
    if (idx < n) {
      const int r = row_idx[e0 + idx];
      const int c = col_idx[e0 + idx];
      ea[j] = adj[e0 + idx];
      eb[j] = r >> RPB_LOG;
      em[j] = ((unsigned)(r & (RPB - 1)) << 17) | (unsigned)c;
      atomicAdd(&sCnt[eb[j]], 1);
    }
  }
  __syncthreads();

  const int v = sCnt[t];
  sScan[t] = v;
  __syncthreads();
  int a = v;
  #pragma unroll
  for (int d = 1; d < 1024; d <<= 1) {
    const int add = (t >= d) ? sScan[t - d] : 0;
    __syncthreads();
    a += add;
    sScan[t] = a;
    __syncthreads();
  }
  const int excl = a - v;
  sScan[t] = excl;
  if (v > 0 && t < NB) sBase[t] = atomicAdd(&cursor[t], v);
  __syncthreads();

  #pragma unroll
  for (int j = 0; j < 4; ++j) {
    if (eb[j] >= 0) {
      const int p = sScan[eb[j]] + atomicAdd(&sFill[eb[j]], 1);
      sMeta[p] = em[j];
      sAdj[p] = ea[j];
      sBkt[p] = (ushort)eb[j];
    }
  }
  __syncthreads();

  #pragma unroll
  for (int j = 0; j < 4; ++j) {
    const int sp = t + j * BIN_BS;
    if (sp < n) {
      const int b = sBkt[sp];
      const int dst = sBase[b] + (sp - sScan[b]);
      int2 o;
      o.x = (int)sMeta[sp];
      o.y = __float_as_int(sAdj[sp]);
      packed[dst] = o;
    }
  }
}

// ---------------------------------------------------------------------------
// Kernel 5: bucket accumulate (NO f32 atomics). Per chunk of <=2560 edges:
// counting-sort by row-in-bucket in LDS (int atomics + 128-bin scan), then
// wave wv exclusively owns rows [wv*8, wv*8+8): reads (col,adj) as uniform
// LDS broadcasts, keeps 8 bf16 gathers in flight, accumulates in REGISTERS,
// one plain LDS add per row. Coalesced fused-ReLU tile store.
// ---------------------------------------------------------------------------
__global__ __launch_bounds__(ACC_BS) void bucket_acc_kernel(
    const int* __restrict__ base, const int2* __restrict__ packed,
    const ushort* __restrict__ hidden, float* __restrict__ out) {
  __shared__ float    accT[RPB * OUT_F];    // 32 KB
  __shared__ unsigned sMeta[ACC_CHUNK];     // 10 KB
  __shared__ float    sAdj[ACC_CHUNK];      // 10 KB
  __shared__ int      rowCnt[RPB];
  __shared__ int      rowOff[RPB + 1];
  __shared__ int      sTmp[RPB];

  const int t = threadIdx.x;
  const int b = blockIdx.x;
  const int lane = t & 63;
  const int wv = t >> 6;  // 0..15

  float4* a4 = (float4*)accT;
  #pragma unroll
  for (int i = 0; i < 2; ++i)
    a4[t + i * ACC_BS] = make_float4(0.f, 0.f, 0.f, 0.f);

  const int s = base[b];
  const int e = base[b + 1];

  for (int g0 = s; g0 < e; g0 += ACC_CHUNK) {
    const int n = min(ACC_CHUNK, e - g0);

    if (t < RPB) rowCnt[t] = 0;
    __syncthreads();

    unsigned m[3];
    float    a[3];
    int      ro[3], pos[3];
    #pragma unroll
    for (int j = 0; j < 3; ++j) {
      const int idx = t + j * ACC_BS;
      ro[j] = -1;
      if (idx < n) {
        const int2 p = packed[g0 + idx];   // coalesced
        m[j] = (unsigned)p.x;
        a[j] = __int_as_float(p.y);
        ro[j] = (int)((m[j] >> 17) & (RPB - 1));
        pos[j] = atomicAdd(&rowCnt[ro[j]], 1);
      }
    }
    __syncthreads();

    if (t < RPB) sTmp[t] = rowCnt[t];
    __syncthreads();
    for (int d = 1; d < RPB; d <<= 1) {
      int add = 0;
      if (t < RPB && t >= d) add = sTmp[t - d];
      __syncthreads();
      if (t < RPB) sTmp[t] += add;
      __syncthreads();
    }
    if (t < RPB) rowOff[t] = sTmp[t] - rowCnt[t];
    if (t == 0) rowOff[RPB] = n;
    __syncthreads();

    #pragma unroll
    for (int j = 0; j < 3; ++j) {
      if (ro[j] >= 0) {
        const int p = rowOff[ro[j]] + pos[j];
        sMeta[p] = m[j];
        sAdj[p] = a[j];
      }
    }
    __syncthreads();

    for (int r = wv * 8; r < wv * 8 + 8; ++r) {
      const int rs = rowOff[r];
      const int re = rowOff[r + 1];
      float acc = 0.0f;
      int i = rs;
      for (; i + 8 <= re; i += 8) {
        float h[8], av[8];
        #pragma unroll
        for (int j = 0; j < 8; ++j) {
          const unsigned mm = sMeta[i + j];   // uniform -> LDS broadcast
          av[j] = sAdj[i + j];
          const int c = (int)(mm & 0x1FFFFu);
          h[j] = __uint_as_float(
              (unsigned)hidden[(size_t)c * OUT_F + lane] << 16);
        }
        #pragma unroll
        for (int j = 0; j < 8; ++j) acc = fmaf(av[j], h[j], acc);
      }
      for (; i < re; ++i) {
        const unsigned mm = sMeta[i];
        const int c = (int)(mm & 0x1FFFFu);
        const float h = __uint_as_float(
            (unsigned)hidden[(size_t)c * OUT_F + lane] << 16);
        acc = fmaf(sAdj[i], h, acc);
      }
      if (acc != 0.0f || rs != re)
        accT[r * OUT_F + lane] += acc;  // plain LDS RMW, single owner
    }
    __syncthreads();  // chunk done before rowCnt/sMeta reuse
  }

  __syncthreads();
  const int rbase = b * RPB;
  float4* o4 = (float4*)(out + (size_t)rbase * OUT_F);
  #pragma unroll
  for (int i = 0; i < 2; ++i) {
    const int idx4 = t + i * ACC_BS;
    const int r = idx4 >> 4;  // 16 float4 per row
    if (rbase + r < N_NODES) {
      float4 vv = a4[idx4];
      vv.x = fmaxf(vv.x, 0.f);
      vv.y = fmaxf(vv.y, 0.f);
      vv.z = fmaxf(vv.z, 0.f);
      vv.w = fmaxf(vv.w, 0.f);
      o4[idx4] = vv;
    }
  }
}

extern "C" void kernel_launch(void* const* d_in, const int* in_sizes, int n_in,
                              void* d_out, int out_size, void* d_ws,
                              size_t ws_size, hipStream_t stream) {
  const float* x       = (const float*)d_in[0];
  const int*   row_idx = (const int*)d_in[1];
  const int*   col_idx = (const int*)d_in[2];
  const float* adj     = (const float*)d_in[3];
  const void*  mask    = d_in[4];
  const float* w       = (const float*)d_in[5];
  const float* bias    = (const float*)d_in[6];
  float* out = (float*)d_out;
  const int nedges = in_sizes[1];

  // ws layout (16B-aligned): hidden bf16 | cnt | base | cursor | packed
  char* ws = (char*)d_ws;
  const size_t off_hidden = 0;
  const size_t sz_hidden  = (size_t)N_NODES * OUT_F * sizeof(ushort);  // 12.8MB
  const size_t off_cnt    = (off_hidden + sz_hidden + 15) & ~(size_t)15;
  const size_t off_base   = (off_cnt + NB * 4 + 15) & ~(size_t)15;
  const size_t off_cursor = (off_base + (NB + 1) * 4 + 15) & ~(size_t)15;
  const size_t off_packed = (off_cursor + NB * 4 + 15) & ~(size_t)15;

  ushort* hidden = (ushort*)(ws + off_hidden);
  int*    cnt    = (int*)(ws + off_cnt);
  int*    base   = (int*)(ws + off_base);
  int*    cursor = (int*)(ws + off_cursor);
  int2*   packed = (int2*)(ws + off_packed);

  gemm_dropout_kernel<<<(N_NODES + G_ROWS - 1) / G_ROWS, G_BS, 0, stream>>>(
      x, w, bias, mask, hidden);

  hipMemsetAsync(cnt, 0, NB * 4, stream);
  hist_kernel<<<512, 256, 0, stream>>>(row_idx, cnt, nedges);
  scan_kernel<<<1, 1024, 0, stream>>>(cnt, base, cursor);
  bin_kernel<<<(nedges + BIN_CHUNK - 1) / BIN_CHUNK, BIN_BS, 0, stream>>>(
      row_idx, col_idx, adj, cursor, packed, nedges);
  bucket_acc_kernel<<<NB, ACC_BS, 0, stream>>>(base, packed, hidden, out);
}

// Round 9
// 117.814 us; speedup vs baseline: 6.8244x; 1.0883x over previous
//
#include <hip/hip_runtime.h>
#include <hip/hip_bf16.h>

#define N_NODES 100000
#define IN_F    128
#define OUT_F   64
#define INV_KEEP (1.0f / 0.9f)

#define RPB_LOG 7                 // rows per bucket = 128
#define RPB (1 << RPB_LOG)
#define NB  ((N_NODES + RPB - 1) / RPB)   // 782 buckets
#define BIN_CHUNK 4096
#define BIN_BS 1024
#define ACC_BS 1024
#define ACC_CHUNK 2560            // edges sorted per pass (avg bucket = 2046)

#define G_BS   128                // gemm block threads
#define G_ROWS 128                // rows per gemm block -> grid 782

// ---------------------------------------------------------------------------
// Kernel 1: hidden = dropout(x @ W + b) -> bf16. Thread owns 4 rows x 16 cols.
// x: direct global->reg float4, software-pipelined, NO barriers in k-loop.
// W: 32 KB LDS, b128 wave-broadcast reads. Grid 782 x 128 threads.
// ---------------------------------------------------------------------------
__global__ __launch_bounds__(G_BS) void gemm_dropout_kernel(
    const float* __restrict__ x, const float* __restrict__ w,
    const float* __restrict__ bias, const void* __restrict__ mask,
    ushort* __restrict__ hidden) {
  __shared__ float wlds[IN_F * OUT_F];   // 32 KB, row-major [k][64]
  __shared__ int mask_is_u8;

  const int tid = threadIdx.x;
  const int rowbase = blockIdx.x * G_ROWS;

  const float4* w4 = (const float4*)w;
  float4* wl4 = (float4*)wlds;
  #pragma unroll
  for (int i = 0; i < 16; ++i)
    wl4[tid + i * G_BS] = w4[tid + i * G_BS];

  // detect drop_mask storage: 1-byte bool vs int32 (deterministic, data-based)
  if (tid < 64) {
    const unsigned char* m8 = (const unsigned char*)mask;
    unsigned long long b = __ballot(m8[tid] != 0);
    if (tid == 0) mask_is_u8 = (__popcll(b) > 32) ? 1 : 0;
  }

  const int j  = tid & 3;          // col group: cols 16j..16j+15
  const int i4 = tid >> 2;         // 0..31
  const int r0 = 4 * i4;           // local row base
  const int c0 = 16 * j;

  const float4 bv0 = *(const float4*)&bias[c0 + 0];
  const float4 bv1 = *(const float4*)&bias[c0 + 4];
  const float4 bv2 = *(const float4*)&bias[c0 + 8];
  const float4 bv3 = *(const float4*)&bias[c0 + 12];

  float4 acc[4][4];  // [row][col-quad]
  #pragma unroll
  for (int r = 0; r < 4; ++r)
    #pragma unroll
    for (int q = 0; q < 4; ++q) acc[r][q] = make_float4(0.f, 0.f, 0.f, 0.f);

  const float* xp[4];
  #pragma unroll
  for (int r = 0; r < 4; ++r) {
    int grow = rowbase + r0 + r;
    grow = (grow < N_NODES) ? grow : (N_NODES - 1);
    xp[r] = x + (size_t)grow * IN_F;
  }

  __syncthreads();  // W staged + mask flag visible

  float4 xq[4];
  #pragma unroll
  for (int r = 0; r < 4; ++r) xq[r] = *(const float4*)(xp[r]);

#define FMA4(A, s, B) \
  A.x = fmaf(s, B.x, A.x); A.y = fmaf(s, B.y, A.y); \
  A.z = fmaf(s, B.z, A.z); A.w = fmaf(s, B.w, A.w)

  #pragma unroll 2
  for (int k0 = 0; k0 < IN_F; k0 += 4) {
    float4 xn[4];
    if (k0 + 4 < IN_F) {
      #pragma unroll
      for (int r = 0; r < 4; ++r)
        xn[r] = *(const float4*)(xp[r] + k0 + 4);
    }
    #pragma unroll
    for (int kk = 0; kk < 4; ++kk) {
      float4 wv[4];
      #pragma unroll
      for (int q = 0; q < 4; ++q)
        wv[q] = *(const float4*)&wlds[(k0 + kk) * OUT_F + c0 + 4 * q];
      const float x0 = (kk == 0) ? xq[0].x : (kk == 1) ? xq[0].y : (kk == 2) ? xq[0].z : xq[0].w;
      const float x1 = (kk == 0) ? xq[1].x : (kk == 1) ? xq[1].y : (kk == 2) ? xq[1].z : xq[1].w;
      const float x2 = (kk == 0) ? xq[2].x : (kk == 1) ? xq[2].y : (kk == 2) ? xq[2].z : xq[2].w;
      const float x3 = (kk == 0) ? xq[3].x : (kk == 1) ? xq[3].y : (kk == 2) ? xq[3].z : xq[3].w;
      #pragma unroll
      for (int q = 0; q < 4; ++q) {
        FMA4(acc[0][q], x0, wv[q]);
        FMA4(acc[1][q], x1, wv[q]);
        FMA4(acc[2][q], x2, wv[q]);
        FMA4(acc[3][q], x3, wv[q]);
      }
    }
    if (k0 + 4 < IN_F) {
      #pragma unroll
      for (int r = 0; r < 4; ++r) xq[r] = xn[r];
    }
  }
#undef FMA4

  // epilogue: bias + dropout + bf16 RNE + packed store
  const unsigned char* m8 = (const unsigned char*)mask;
  const int* m32 = (const int*)mask;
  const int u8mode = mask_is_u8;

  #pragma unroll
  for (int r = 0; r < 4; ++r) {
    const int grow = rowbase + r0 + r;
    if (grow < N_NODES) {
      const size_t mbase = (size_t)grow * OUT_F + c0;
      unsigned keep[16];
      if (u8mode) {
        const uint4 mv = *(const uint4*)(m8 + mbase);  // 16 bytes, aligned
        #pragma unroll
        for (int b = 0; b < 4; ++b) {
          keep[0 + b]  = (mv.x >> (8 * b)) & 255u;
          keep[4 + b]  = (mv.y >> (8 * b)) & 255u;
          keep[8 + b]  = (mv.z >> (8 * b)) & 255u;
          keep[12 + b] = (mv.w >> (8 * b)) & 255u;
        }
      } else {
        #pragma unroll
        for (int q = 0; q < 4; ++q) {
          const int4 mv = *(const int4*)(m32 + mbase + 4 * q);
          keep[4 * q + 0] = (unsigned)mv.x;
          keep[4 * q + 1] = (unsigned)mv.y;
          keep[4 * q + 2] = (unsigned)mv.z;
          keep[4 * q + 3] = (unsigned)mv.w;
        }
      }
      float vals[16];
      #pragma unroll
      for (int q = 0; q < 4; ++q) {
        const float4 a = acc[r][q];
        const float4 bb = (q == 0) ? bv0 : (q == 1) ? bv1 : (q == 2) ? bv2 : bv3;
        vals[4 * q + 0] = a.x + bb.x;
        vals[4 * q + 1] = a.y + bb.y;
        vals[4 * q + 2] = a.z + bb.z;
        vals[4 * q + 3] = a.w + bb.w;
      }
      unsigned hw[8];
      #pragma unroll
      for (int p = 0; p < 8; ++p) {
        float v0 = keep[2 * p]     ? vals[2 * p] * INV_KEEP     : 0.f;
        float v1 = keep[2 * p + 1] ? vals[2 * p + 1] * INV_KEEP : 0.f;
        unsigned u0 = __float_as_uint(v0);
        u0 += 0x7FFFu + ((u0 >> 16) & 1u);
        unsigned u1 = __float_as_uint(v1);
        u1 += 0x7FFFu + ((u1 >> 16) & 1u);
        hw[p] = (u0 >> 16) | (u1 & 0xFFFF0000u);
      }
      uint4* dst = (uint4*)&hidden[mbase];
      dst[0] = make_uint4(hw[0], hw[1], hw[2], hw[3]);
      dst[1] = make_uint4(hw[4], hw[5], hw[6], hw[7]);
    }
  }
}

// ---------------------------------------------------------------------------
// Kernel 2: bucket histogram (LDS-staged)
// ---------------------------------------------------------------------------
__global__ __launch_bounds__(256) void hist_kernel(
    const int* __restrict__ row_idx, int* __restrict__ cnt, int nedges) {
  __shared__ int hc[NB];
  const int t = threadIdx.x;
  for (int i = t; i < NB; i += 256) hc[i] = 0;
  __syncthreads();
  const int stride = gridDim.x * 256;
  for (int e = blockIdx.x * 256 + t; e < nedges; e += stride)
    atomicAdd(&hc[row_idx[e] >> RPB_LOG], 1);
  __syncthreads();
  for (int i = t; i < NB; i += 256)
    if (hc[i]) atomicAdd(&cnt[i], hc[i]);
}

// ---------------------------------------------------------------------------
// Kernel 3: one-block scan of NB counts -> base[NB+1], cursor[NB]
// ---------------------------------------------------------------------------
__global__ __launch_bounds__(1024) void scan_kernel(
    const int* __restrict__ cnt, int* __restrict__ base,
    int* __restrict__ cursor) {
  __shared__ int s[1024];
  const int t = threadIdx.x;
  const int v = (t < NB) ? cnt[t] : 0;
  s[t] = v;
  __syncthreads();
  int a = v;
  #pragma unroll
  for (int d = 1; d < 1024; d <<= 1) {
    const int add = (t >= d) ? s[t - d] : 0;
    __syncthreads();
    a += add;
    s[t] = a;
    __syncthreads();
  }
  if (t < NB) {
    base[t] = a - v;
    cursor[t] = a - v;
  }
  if (t == NB - 1) base[NB] = a;
}

// ---------------------------------------------------------------------------
// Kernel 4: bin — LDS counting-sort a 4096-edge chunk by bucket, then write
// coalesced runs into each bucket's reserved global range.
// meta = ((row & 127) << 17) | col   (24 bits), adj kept f32.
// ---------------------------------------------------------------------------
__global__ __launch_bounds__(BIN_BS) void bin_kernel(
    const int* __restrict__ row_idx, const int* __restrict__ col_idx,
    const float* __restrict__ adj, int* __restrict__ cursor,
    int2* __restrict__ packed, int nedges) {
  __shared__ unsigned sMeta[BIN_CHUNK];   // 16 KB
  __shared__ float    sAdj[BIN_CHUNK];    // 16 KB
  __shared__ ushort   sBkt[BIN_CHUNK];    //  8 KB
  __shared__ int      sCnt[1024];         //  4 KB
  __shared__ int      sScan[1024];        //  4 KB
  __shared__ int      sBase[1024];        //  4 KB
  __shared__ int      sFill[1024];        //  4 KB

  const int t = threadIdx.x;
  const int e0 = blockIdx.x * BIN_CHUNK;
  const int n = min(BIN_CHUNK, nedges - e0);

  sCnt[t] = 0;
  sBase[t] = 0;
  sFill[t] = 0;
  __syncthreads();

  int      eb[4];
  unsigned em[4];
  float    ea[4];
  #pragma unroll
  for (int j = 0; j < 4; ++j) {
    const int idx = t + j * BIN_BS;
    eb[j] = -1;
    if (idx < n) {
      const int r = row_idx[e0 + idx];
      const int c = col_idx[e0 + idx];
      ea[j] = adj[e0 + idx];
      eb[j] = r >> RPB_LOG;
      em[j] = ((unsigned)(r & (RPB - 1)) << 17) | (unsigned)c;
      atomicAdd(&sCnt[eb[j]], 1);
    }
  }
  __syncthreads();

  const int v = sCnt[t];
  sScan[t] = v;
  __syncthreads();
  int a = v;
  #pragma unroll
  for (int d = 1; d < 1024; d <<= 1) {
    const int add = (t >= d) ? sScan[t - d] : 0;
    __syncthreads();
    a += add;
    sScan[t] = a;
    __syncthreads();
  }
  const int excl = a - v;
  sScan[t] = excl;
  if (v > 0 && t < NB) sBase[t] = atomicAdd(&cursor[t], v);
  __syncthreads();

  #pragma unroll
  for (int j = 0; j < 4; ++j) {
    if (eb[j] >= 0) {
      const int p = sScan[eb[j]] + atomicAdd(&sFill[eb[j]], 1);
      sMeta[p] = em[j];
      sAdj[p] = ea[j];
      sBkt[p] = (ushort)eb[j];
    }
  }
  __syncthreads();

  #pragma unroll
  for (int j = 0; j < 4; ++j) {
    const int sp = t + j * BIN_BS;
    if (sp < n) {
      const int b = sBkt[sp];
      const int dst = sBase[b] + (sp - sScan[b]);
      int2 o;
      o.x = (int)sMeta[sp];
      o.y = __float_as_int(sAdj[sp]);
      packed[dst] = o;
    }
  }
}

// ---------------------------------------------------------------------------
// Kernel 5: bucket accumulate. Pair-gather: lane&31 = feat-pair (dword of 2
// bf16), lane>>5 = edge parity -> one global_load_dword serves 2 edges.
// Metadata packed int2 in LDS (1 ds_read_b64/edge). Row sums in registers,
// __shfl_xor(32) half-combine, one predicated float2 LDS RMW per row.
// ---------------------------------------------------------------------------
__global__ __launch_bounds__(ACC_BS) void bucket_acc_kernel(
    const int* __restrict__ base, const int2* __restrict__ packed,
    const ushort* __restrict__ hidden, float* __restrict__ out) {
  __shared__ float accT[RPB * OUT_F];    // 32 KB
  __shared__ int2  sEdge[ACC_CHUNK];     // 20 KB (meta, adj-bits)
  __shared__ int   rowCnt[RPB];
  __shared__ int   rowOff[RPB + 1];
  __shared__ int   sTmp[RPB];

  const int t = threadIdx.x;
  const int b = blockIdx.x;
  const int lane = t & 63;
  const int half = lane >> 5;      // 0: even edge of pair, 1: odd edge
  const int fl = lane & 31;        // feat-pair index (feats 2fl, 2fl+1)
  const int wv = t >> 6;           // 0..15

  const unsigned* __restrict__ hid32 = (const unsigned*)hidden; // [node][32]

  float4* a4 = (float4*)accT;
  #pragma unroll
  for (int i = 0; i < 2; ++i)
    a4[t + i * ACC_BS] = make_float4(0.f, 0.f, 0.f, 0.f);

  const int s = base[b];
  const int e = base[b + 1];

  for (int g0 = s; g0 < e; g0 += ACC_CHUNK) {
    const int n = min(ACC_CHUNK, e - g0);

    if (t < RPB) rowCnt[t] = 0;
    __syncthreads();

    // load up to 3 edges/thread (coalesced), count rows (int LDS atomics)
    int2 ev[3];
    int  ro[3], pos[3];
    #pragma unroll
    for (int j = 0; j < 3; ++j) {
      const int idx = t + j * ACC_BS;
      ro[j] = -1;
      if (idx < n) {
        ev[j] = packed[g0 + idx];
        ro[j] = (int)(((unsigned)ev[j].x >> 17) & (RPB - 1));
        pos[j] = atomicAdd(&rowCnt[ro[j]], 1);
      }
    }
    __syncthreads();

    // exclusive scan of 128 row counts
    if (t < RPB) sTmp[t] = rowCnt[t];
    __syncthreads();
    for (int d = 1; d < RPB; d <<= 1) {
      int add = 0;
      if (t < RPB && t >= d) add = sTmp[t - d];
      __syncthreads();
      if (t < RPB) sTmp[t] += add;
      __syncthreads();
    }
    if (t < RPB) rowOff[t] = sTmp[t] - rowCnt[t];
    if (t == 0) rowOff[RPB] = n;
    __syncthreads();

    // scatter into row-sorted LDS positions (1 ds_write_b64 per edge)
    #pragma unroll
    for (int j = 0; j < 3; ++j) {
      if (ro[j] >= 0) sEdge[rowOff[ro[j]] + pos[j]] = ev[j];
    }
    __syncthreads();

    // accumulate: wave wv owns rows wv*8 .. wv*8+7
    for (int r = wv * 8; r < wv * 8 + 8; ++r) {
      const int rs = rowOff[r];
      const int re = rowOff[r + 1];
      if (rs == re) continue;
      float acc0 = 0.f, acc1 = 0.f;
      int i = rs;
      // 4 pairs (8 edges) per group: 4 loads in flight
      for (; i + 8 <= re; i += 8) {
        unsigned g[4];
        float    av[4];
        #pragma unroll
        for (int p = 0; p < 4; ++p) {
          const int2 e0 = sEdge[i + 2 * p];
          const int2 e1 = sEdge[i + 2 * p + 1];
          const int c = (half ? e1.x : e0.x) & 0x1FFFF;
          av[p] = __int_as_float(half ? e1.y : e0.y);
          g[p] = hid32[c * 32 + fl];
        }
        #pragma unroll
        for (int p = 0; p < 4; ++p) {
          acc0 = fmaf(av[p], __uint_as_float(g[p] << 16), acc0);
          acc1 = fmaf(av[p], __uint_as_float(g[p] & 0xFFFF0000u), acc1);
        }
      }
      for (; i + 2 <= re; i += 2) {
        const int2 e0 = sEdge[i];
        const int2 e1 = sEdge[i + 1];
        const int c = (half ? e1.x : e0.x) & 0x1FFFF;
        const float av = __int_as_float(half ? e1.y : e0.y);
        const unsigned g = hid32[c * 32 + fl];
        acc0 = fmaf(av, __uint_as_float(g << 16), acc0);
        acc1 = fmaf(av, __uint_as_float(g & 0xFFFF0000u), acc1);
      }
      if (i < re) {  // odd residue: hi half contributes zero
        const int2 e0 = sEdge[i];
        const int c = e0.x & 0x1FFFF;
        const float av = half ? 0.0f : __int_as_float(e0.y);
        const unsigned g = hid32[c * 32 + fl];
        acc0 = fmaf(av, __uint_as_float(g << 16), acc0);
        acc1 = fmaf(av, __uint_as_float(g & 0xFFFF0000u), acc1);
      }
      // combine the two halves (lane l <-> l^32), lo half commits
      acc0 += __shfl_xor(acc0, 32);
      acc1 += __shfl_xor(acc1, 32);
      if (half == 0) {
        float2* dst = (float2*)&accT[r * OUT_F + 2 * fl];
        float2 v = *dst;
        v.x += acc0;
        v.y += acc1;
        *dst = v;
      }
    }
    __syncthreads();  // chunk done before rowCnt/sEdge reuse
  }

  __syncthreads();
  const int rbase = b * RPB;
  float4* o4 = (float4*)(out + (size_t)rbase * OUT_F);
  #pragma unroll
  for (int i = 0; i < 2; ++i) {
    const int idx4 = t + i * ACC_BS;
    const int r = idx4 >> 4;  // 16 float4 per row
    if (rbase + r < N_NODES) {
      float4 vv = a4[idx4];
      vv.x = fmaxf(vv.x, 0.f);
      vv.y = fmaxf(vv.y, 0.f);
      vv.z = fmaxf(vv.z, 0.f);
      vv.w = fmaxf(vv.w, 0.f);
      o4[idx4] = vv;
    }
  }
}

extern "C" void kernel_launch(void* const* d_in, const int* in_sizes, int n_in,
                              void* d_out, int out_size, void* d_ws,
                              size_t ws_size, hipStream_t stream) {
  const float* x       = (const float*)d_in[0];
  const int*   row_idx = (const int*)d_in[1];
  const int*   col_idx = (const int*)d_in[2];
  const float* adj     = (const float*)d_in[3];
  const void*  mask    = d_in[4];
  const float* w       = (const float*)d_in[5];
  const float* bias    = (const float*)d_in[6];
  float* out = (float*)d_out;
  const int nedges = in_sizes[1];

  // ws layout (16B-aligned): hidden bf16 | cnt | base | cursor | packed
  char* ws = (char*)d_ws;
  const size_t off_hidden = 0;
  const size_t sz_hidden  = (size_t)N_NODES * OUT_F * sizeof(ushort);  // 12.8MB
  const size_t off_cnt    = (off_hidden + sz_hidden + 15) & ~(size_t)15;
  const size_t off_base   = (off_cnt + NB * 4 + 15) & ~(size_t)15;
  const size_t off_cursor = (off_base + (NB + 1) * 4 + 15) & ~(size_t)15;
  const size_t off_packed = (off_cursor + NB * 4 + 15) & ~(size_t)15;

  ushort* hidden = (ushort*)(ws + off_hidden);
  int*    cnt    = (int*)(ws + off_cnt);
  int*    base   = (int*)(ws + off_base);
  int*    cursor = (int*)(ws + off_cursor);
  int2*   packed = (int2*)(ws + off_packed);

  gemm_dropout_kernel<<<(N_NODES + G_ROWS - 1) / G_ROWS, G_BS, 0, stream>>>(
      x, w, bias, mask, hidden);

  hipMemsetAsync(cnt, 0, NB * 4, stream);
  hist_kernel<<<512, 256, 0, stream>>>(row_idx, cnt, nedges);
  scan_kernel<<<1, 1024, 0, stream>>>(cnt, base, cursor);
  bin_kernel<<<(nedges + BIN_CHUNK - 1) / BIN_CHUNK, BIN_BS, 0, stream>>>(
      row_idx, col_idx, adj, cursor, packed, nedges);
  bucket_acc_kernel<<<NB, ACC_BS, 0, stream>>>(base, packed, hidden, out);
}